// Round 10
// baseline (65.200 us; speedup 1.0000x reference)
//
#include <hip/hip_runtime.h>

// Dist_Conv2D_Dense: Chebyshev (L-inf) distance "conv".
// B=8, Cin=16, H=W=64, Cout=32, K=3, stride=1, edge-replicate pad.
// out[b][co][h][w] = max_{cin,kh,kw} |x[b][cin][clamp(h+kh-1)][clamp(w+kw-1)]
//                                    - wt[co][cin][kh][kw]|  + bias[co]
//
// Round-9 (resubmit): XCD-locality fix. Old decode (g=bid&7) put each
// cout-group on its own XCD (xcd=bid&7 under round-robin dispatch) -> every
// XCD cold-fetched ALL of x from HBM after the harness's 256MB L3-wiping
// re-poison fill. New decode (g=bid>>7, pblk=bid&127) co-locates all 8
// cout-groups of a pixel-block on one XCD -> each XCD first-touches only its
// 1/8 x slice; sibling groups hit local L2. Else identical to round-7/8.

constexpr int Bn = 8, Cin = 16, Hn = 64, Wn = 64, Cout = 32;
constexpr int CPT = 4;            // couts per thread
constexpr int NG  = Cout / CPT;   // 8 cout groups
constexpr int BLOCK = 256;

__global__ __launch_bounds__(BLOCK, 4)   // 4 waves/EU min -> >=4 blocks/CU resident
void dist_conv_kernel(const float* __restrict__ x,
                      const float* __restrict__ wt,
                      const float* __restrict__ bias,
                      float* __restrict__ out) {
    // weights for this block's 4 couts: [cin*9 + k] -> float4 over couts
    __shared__ float4 wl[Cin * 9];

    // XCD-aware decode: consecutive bids = consecutive pixel blocks ->
    // round-robin dispatch gives each XCD a disjoint pixel slice, and all
    // 8 cout-groups of pixel-block p land on XCD (p & 7).
    const int g    = blockIdx.x >> 7;         // cout group 0..7
    const int pblk = blockIdx.x & 127;        // pixel block 0..127

    // Stage weights: 16*9*4 = 576 floats, transposed to [cin][k][c]
    for (int i = threadIdx.x; i < Cin * 9 * CPT; i += BLOCK) {
        const int cin = i / (9 * CPT);
        const int rem = i % (9 * CPT);
        const int k   = rem / CPT;
        const int c   = rem % CPT;
        reinterpret_cast<float*>(wl)[(cin * 9 + k) * CPT + c] =
            wt[((g * CPT + c) * Cin + cin) * 9 + k];
    }
    __syncthreads();

    // one pixel per thread
    const int p  = pblk * BLOCK + threadIdx.x;    // 0..32767
    const int w0 = p & 63;
    const int h  = (p >> 6) & 63;
    const int b  = p >> 12;

    const int hm = max(h - 1, 0) * Wn;
    const int h0 = h * Wn;
    const int hp = min(h + 1, Hn - 1) * Wn;
    const int cm = max(w0 - 1, 0);
    const int cp = min(w0 + 1, Wn - 1);

    float acc[CPT] = {0.f, 0.f, 0.f, 0.f};

    const float* xb = x + b * (Cin * Hn * Wn);
#pragma unroll
    for (int cin = 0; cin < Cin; ++cin) {
        const float* xc = xb + cin * (Hn * Wn);
        float xr[3][3];
        xr[0][0] = xc[hm + cm]; xr[0][1] = xc[hm + w0]; xr[0][2] = xc[hm + cp];
        xr[1][0] = xc[h0 + cm]; xr[1][1] = xc[h0 + w0]; xr[1][2] = xc[h0 + cp];
        xr[2][0] = xc[hp + cm]; xr[2][1] = xc[hp + w0]; xr[2][2] = xc[hp + cp];
#pragma unroll
        for (int kh = 0; kh < 3; ++kh) {
#pragma unroll
            for (int kw = 0; kw < 3; ++kw) {
                const float4 wv = wl[cin * 9 + kh * 3 + kw];
                const float xa = xr[kh][kw];
                acc[0] = fmaxf(acc[0], fabsf(xa - wv.x));
                acc[1] = fmaxf(acc[1], fabsf(xa - wv.y));
                acc[2] = fmaxf(acc[2], fabsf(xa - wv.z));
                acc[3] = fmaxf(acc[3], fabsf(xa - wv.w));
            }
        }
    }

    float* ob = out + b * (Cout * Hn * Wn) + h0 + w0;
#pragma unroll
    for (int c = 0; c < CPT; ++c) {
        const int co = g * CPT + c;
        ob[co * (Hn * Wn)] = acc[c] + bias[co];
    }
}

extern "C" void kernel_launch(void* const* d_in, const int* in_sizes, int n_in,
                              void* d_out, int out_size, void* d_ws, size_t ws_size,
                              hipStream_t stream) {
    const float* x    = (const float*)d_in[0];
    const float* wt   = (const float*)d_in[1];
    const float* bias = (const float*)d_in[2];
    float* out        = (float*)d_out;

    // grid: 8 cout-groups * (8*64*64 pixels / 256 threads) = 8*128 = 1024 blocks
    const int pixels = Bn * Hn * Wn;               // 32768
    const int grid   = NG * (pixels / BLOCK);      // 1024
    dist_conv_kernel<<<grid, BLOCK, 0, stream>>>(x, wt, bias, out);
}